// Round 20
// baseline (302.587 us; speedup 1.0000x reference)
//
#include <hip/hip_runtime.h>
#include <cstdint>
#include <cstddef>

#define NEGF (-1e30f)
#define LOG2E 1.4426950408889634f
#define LN2 0.6931471805599453f

typedef __attribute__((ext_vector_type(8))) short short8;
typedef __attribute__((ext_vector_type(4))) float f32x4;

// round-to-nearest-even fp32 -> bf16 bits
__device__ __forceinline__ unsigned short f2bf(float f) {
  unsigned int u = __float_as_uint(f);
  u += 0x7fffu + ((u >> 16) & 1u);
  return (unsigned short)(u >> 16);
}

__device__ __forceinline__ void gload_lds16(const void* g, void* l) {
  __builtin_amdgcn_global_load_lds(
      (const __attribute__((address_space(1))) void*)g,
      (__attribute__((address_space(3))) void*)l, 16, 0, 0);
}

__device__ __forceinline__ float fexp2(float x) { return __builtin_amdgcn_exp2f(x); }
__device__ __forceinline__ float flog2(float x) { return __builtin_amdgcn_logf(x); }

// full-wave shift-up-by-1 via DPP wave_shr:1 (full-rate VALU).
// lane i gets lane i-1; lane 0 gets `fill` (old operand, bound_ctrl=false).
__device__ __forceinline__ float wave_shr1(float x, float fill) {
  int r = __builtin_amdgcn_update_dpp(__float_as_int(fill), __float_as_int(x),
                                      0x138, 0xF, 0xF, false);
  return __int_as_float(r);
}

// log-sum-exp of 3 in log2 domain; max term is exp2(0)=1 exactly -> only 2 exp2.
__device__ __forceinline__ float lse3_2(float a, float b, float c) {
  float m  = fmaxf(fmaxf(a, b), c);                 // v_max3
  float md = __builtin_amdgcn_fmed3f(a, b, c);      // v_med3
  float mn = fminf(fminf(a, b), c);                 // v_min3
  return m + flog2(fexp2(md - m) + fexp2(mn - m) + 1.0f);
}

// ---------------- convert kernels (W1, W2 only; X is fused into gemm1f) ----------------
__global__ void k_cvt(const float* __restrict__ src, unsigned short* __restrict__ dst, long n) {
  long i = ((long)blockIdx.x * blockDim.x + threadIdx.x) * 4;
  long stride = (long)gridDim.x * blockDim.x * 4;
  for (; i < n; i += stride) {
    float4 v = *(const float4*)(src + i);
    ushort4 o;
    o.x = f2bf(v.x); o.y = f2bf(v.y); o.z = f2bf(v.z); o.w = f2bf(v.w);
    *(ushort4*)(dst + i) = o;
  }
}

// W2 [101][512] fp32 -> padded [128][512] bf16 (rows >=101 zero)
__global__ void k_cvt_w2(const float* __restrict__ w2, unsigned short* __restrict__ dst) {
  int i = (blockIdx.x * blockDim.x + threadIdx.x) * 4;
  if (i >= 128 * 512) return;
  int c = i >> 9;
  float4 v = make_float4(0.f, 0.f, 0.f, 0.f);
  if (c < 101) v = *(const float4*)(w2 + i);
  ushort4 o;
  o.x = f2bf(v.x); o.y = f2bf(v.y); o.z = f2bf(v.z); o.w = f2bf(v.w);
  *(ushort4*)(dst + i) = o;
}

// ---------------- GEMM1 (fused X-convert): H = relu(X @ W1^T + b1) ----------------
// DEAD-ROW SKIP: CTC only reads t < dlen[b]. Blocks fully inside a batch's dead
// zone early-exit (skipped H rows keep poison; gemm2 skips the same blocks).
__global__ __launch_bounds__(512, 1) void k_gemm1f(
    const float* __restrict__ X,
    const unsigned short* __restrict__ B,
    const float* __restrict__ b1,
    const int* __restrict__ dlen,
    unsigned short* __restrict__ H) {
  __shared__ __align__(16) char ldsA[128 * 144];   // 18432 B
  __shared__ __align__(16) char ldsB[65536];       // [512][64] bf16
  const int K = 1024;
  int r0 = blockIdx.x * 128;
  {
    int b0 = r0 / 1000;
    int rl = r0 - b0 * 1000;
    if (rl <= 872 && rl >= dlen[b0]) return;
  }
  int tid = threadIdx.x;
  int lane = tid & 63, wid = tid >> 6;   // 8 waves
  int wr = (wid & 1) * 64;               // wave row offset: 0 or 64
  int wc = (wid >> 1) * 128;             // wave col offset: 0,128,256,384

  f32x4 acc[4][8];
#pragma unroll
  for (int i = 0; i < 4; ++i)
#pragma unroll
    for (int j = 0; j < 8; ++j) acc[i][j] = (f32x4){0.f, 0.f, 0.f, 0.f};

  int arow = tid >> 2;           // 0..127
  int akoff = (tid & 3) * 16;    // float offset within BK=64: 0,16,32,48

  for (int kt = 0; kt < 16; ++kt) {
    int k0 = kt * 64;
    __syncthreads();
    // stage A: 16 fp32 -> 16 bf16 per thread, two b128 writes, stride-144 layout
    {
      const float* ap = X + (size_t)(r0 + arow) * K + (k0 + akoff);
      float4 av0 = *(const float4*)(ap + 0);
      float4 av1 = *(const float4*)(ap + 4);
      float4 av2 = *(const float4*)(ap + 8);
      float4 av3 = *(const float4*)(ap + 12);
      short8 as0, as1;
      as0[0] = (short)f2bf(av0.x); as0[1] = (short)f2bf(av0.y);
      as0[2] = (short)f2bf(av0.z); as0[3] = (short)f2bf(av0.w);
      as0[4] = (short)f2bf(av1.x); as0[5] = (short)f2bf(av1.y);
      as0[6] = (short)f2bf(av1.z); as0[7] = (short)f2bf(av1.w);
      as1[0] = (short)f2bf(av2.x); as1[1] = (short)f2bf(av2.y);
      as1[2] = (short)f2bf(av2.z); as1[3] = (short)f2bf(av2.w);
      as1[4] = (short)f2bf(av3.x); as1[5] = (short)f2bf(av3.y);
      as1[6] = (short)f2bf(av3.z); as1[7] = (short)f2bf(av3.w);
      int ab = arow * 144 + akoff * 2;
      *(short8*)(ldsA + ab) = as0;
      *(short8*)(ldsA + ab + 16) = as1;
    }
    // stage B: 512x64 bf16 via gload_lds, pre-swizzled source chunks
#pragma unroll
    for (int r = 0; r < 8; ++r) {
      int c = r * 512 + tid;
      int trow = c >> 3;                  // 0..511 (output col)
      int sch = (c & 7) ^ (trow & 7);
      gload_lds16(B + (size_t)trow * K + (k0 + sch * 8), ldsB + c * 16);
    }
    asm volatile("s_waitcnt vmcnt(0)" ::: "memory");
    __syncthreads();
#pragma unroll
    for (int kk = 0; kk < 2; ++kk) {
      int kb2 = (kk * 32 + ((lane >> 4) << 3)) * 2;  // byte offset along K
      short8 af[4], bfr[8];
#pragma unroll
      for (int i = 0; i < 4; ++i) {
        int ar = wr + i * 16 + (lane & 15);
        af[i] = *(const short8*)(ldsA + (ar * 144 + kb2));
      }
#pragma unroll
      for (int j = 0; j < 8; ++j) {
        int br = wc + j * 16 + (lane & 15);
        bfr[j] = *(const short8*)(ldsB + ((br * 128 + kb2) ^ ((br & 7) << 4)));
      }
#pragma unroll
      for (int i = 0; i < 4; ++i)
#pragma unroll
        for (int j = 0; j < 8; ++j)
          acc[i][j] = __builtin_amdgcn_mfma_f32_16x16x32_bf16(af[i], bfr[j], acc[i][j], 0, 0, 0);
    }
  }
  int cl = lane & 15, r4 = (lane >> 4) << 2;
#pragma unroll
  for (int i = 0; i < 4; ++i) {
    int row = r0 + wr + i * 16 + r4;
#pragma unroll
    for (int j = 0; j < 8; ++j) {
      int col = wc + j * 16 + cl;
      float bb = b1[col];
#pragma unroll
      for (int q = 0; q < 4; ++q) {
        float v = acc[i][j][q] + bb;
        v = v > 0.f ? v : 0.f;
        H[(size_t)(row + q) * 512 + col] = f2bf(v);
      }
    }
  }
}

// ---------------- GEMM2 + log_softmax + FUSED TRANSPOSE ----------------
// Hm[64000][512] bf16, W2[128][512] bf16 (padded); writes LPT[b][c][t] fp32*log2e
// directly (acc q-dim = 4 consecutive t at fixed col -> one aligned float4).
__global__ __launch_bounds__(256) void k_gemm2(
    const unsigned short* __restrict__ Hm,
    const unsigned short* __restrict__ W2,
    const float* __restrict__ b2,
    const int* __restrict__ dlen,
    float* __restrict__ LPT) {
  __shared__ __align__(16) char lds[32768];
  const int K = 512;
  int row0 = blockIdx.x * 128;
  {
    int b0 = row0 / 1000;
    int rl = row0 - b0 * 1000;
    if (rl <= 872 && rl >= dlen[b0]) return;
  }
  int tid = threadIdx.x, lane = tid & 63, wid = tid >> 6;
  f32x4 acc[2][8];
#pragma unroll
  for (int i = 0; i < 2; ++i)
#pragma unroll
    for (int j = 0; j < 8; ++j) acc[i][j] = (f32x4){0.f, 0.f, 0.f, 0.f};

  for (int kt = 0; kt < 8; ++kt) {
    int k0 = kt * 64;
    __syncthreads();
#pragma unroll
    for (int r = 0; r < 4; ++r) {
      int c = r * 256 + tid;
      int trow = c >> 3;
      int sch = (c & 7) ^ (trow & 7);
      gload_lds16(Hm + (size_t)(row0 + trow) * K + (k0 + sch * 8), lds + c * 16);
      gload_lds16(W2 + (size_t)trow * K + (k0 + sch * 8), lds + 16384 + c * 16);
    }
    asm volatile("s_waitcnt vmcnt(0)" ::: "memory");
    __syncthreads();
#pragma unroll
    for (int kk = 0; kk < 2; ++kk) {
      int kb2 = (kk * 32 + ((lane >> 4) << 3)) * 2;
      short8 af[2], bfr[8];
#pragma unroll
      for (int i = 0; i < 2; ++i) {
        int ar = wid * 32 + i * 16 + (lane & 15);
        af[i] = *(const short8*)(lds + ((ar * 128 + kb2) ^ ((ar & 7) << 4)));
      }
#pragma unroll
      for (int j = 0; j < 8; ++j) {
        int br = j * 16 + (lane & 15);
        bfr[j] = *(const short8*)(lds + 16384 + ((br * 128 + kb2) ^ ((br & 7) << 4)));
      }
#pragma unroll
      for (int i = 0; i < 2; ++i)
#pragma unroll
        for (int j = 0; j < 8; ++j)
          acc[i][j] = __builtin_amdgcn_mfma_f32_16x16x32_bf16(af[i], bfr[j], acc[i][j], 0, 0, 0);
    }
  }
  // epilogue: bias + row log_softmax (per q), then transposed float4 stores
  int cl = lane & 15, r4 = (lane >> 4) << 2;
#pragma unroll
  for (int i = 0; i < 2; ++i) {
    float outv[4][8];
#pragma unroll
    for (int q = 0; q < 4; ++q) {
      float v[8];
      float mx = NEGF;
#pragma unroll
      for (int j = 0; j < 8; ++j) {
        int col = j * 16 + cl;
        float t = acc[i][j][q];
        if (col < 101) {
          t += b2[col];
          mx = fmaxf(mx, t);
        }
        v[j] = t;
      }
#pragma unroll
      for (int m = 1; m < 16; m <<= 1) mx = fmaxf(mx, __shfl_xor(mx, m));
      float s = 0.f;
#pragma unroll
      for (int j = 0; j < 8; ++j) {
        int col = j * 16 + cl;
        if (col < 101) s += __expf(v[j] - mx);
      }
#pragma unroll
      for (int m = 1; m < 16; m <<= 1) s += __shfl_xor(s, m);
      float lse = mx + __logf(s);
#pragma unroll
      for (int j = 0; j < 8; ++j) outv[q][j] = (v[j] - lse) * LOG2E;
    }
    int row = row0 + wid * 32 + i * 16 + r4;  // base row for q=0..3
    int bb = row / 1000;
    int t = row - bb * 1000;                   // multiple of 4
    float* outp = LPT + (size_t)bb * 101000 + t;
#pragma unroll
    for (int j = 0; j < 8; ++j) {
      int col = j * 16 + cl;
      if (col < 101) {
        float4 o = make_float4(outv[0][j], outv[1][j], outv[2][j], outv[3][j]);
        *(float4*)(outp + col * 1000) = o;
      }
    }
  }
}

// ---------------- CTC: 2 batch elements per block (8 waves), halo exchange ----------------
// Waves 0-3 = batch 2k, waves 4-7 = batch 2k+1 -> 2 waves/SIMD so one batch's
// issue fills the other's chain stalls. Per-batch structure identical to the
// verified 4-wave halo kernel. Loop bound = max(TbA,TbB) block-uniform; STEP
// guards per-batch (frozen batch keeps exporting its final alphas = ref freeze).
__global__ __launch_bounds__(512, 1) void k_ctc(
    const float* __restrict__ LPT,
    const int* __restrict__ tgt_all,
    const int* __restrict__ dlen,
    const int* __restrict__ tlen,
    float* __restrict__ lossout) {
  int tid = threadIdx.x;
  int lane = tid & 63, wid = tid >> 6;
  int grp = wid >> 2, w4 = wid & 3;
  int b = blockIdx.x * 2 + grp;
  const float* lpt = LPT + (size_t)b * 101000;
  int TbA = dlen[blockIdx.x * 2], TbB = dlen[blockIdx.x * 2 + 1];
  int Tmax = max(TbA, TbB);
  int Tb = grp ? TbB : TbA;
  int Ub = tlen[b];
  const int* tg = tgt_all + b * 200;

  int h = (w4 == 0) ? 0 : 16;
  int S0 = 101 * w4 - h;
  int g0 = S0 + 2 * lane;  // state of al0; al1 is g0+1

  int cls[2], sk[2];
#pragma unroll
  for (int j = 0; j < 2; ++j) {
    int s = g0 + j;
    int c = 100, skp = 0;
    if (s >= 0 && s < 401 && (s & 1)) {
      int u = (s - 1) >> 1;
      c = tg[u];
      if (s >= 3) skp = (tg[u] != tg[u - 1]) ? 1 : 0;
    }
    cls[j] = c; sk[j] = skp;
  }

  const float* pa = lpt + cls[0] * 1000;  // 16B-aligned class rows
  const float* pb = lpt + cls[1] * 1000;

  float al0 = (g0 == 0) ? pa[0] : NEGF;  // t=0: only s=0,1 start
  float al1 = (g0 == 0) ? pb[0] : NEGF;

  int slot_base = (w4 == 0) ? 85 : 101;
  int e0 = 2 * lane - slot_base;  // for al0; al1 -> e0+1

  __shared__ float bnd[2][2][3][16];  // [buf][group][producer w4][16]
  __shared__ float sal[2][408];

  // rotating 2-block prefetch: lo = rows [8k,8k+8), hi = rows [8k+8,8k+16)
  float4 a_lo0 = *(const float4*)(pa + 0),  a_lo1 = *(const float4*)(pa + 4);
  float4 a_hi0 = *(const float4*)(pa + 8),  a_hi1 = *(const float4*)(pa + 12);
  float4 b_lo0 = *(const float4*)(pb + 0),  b_lo1 = *(const float4*)(pb + 4);
  float4 b_hi0 = *(const float4*)(pb + 8),  b_hi1 = *(const float4*)(pb + 12);

#define STEP(tt, PA, PB)                                                  \
  do {                                                                    \
    if ((tt) < Tb) {                                                      \
      float u1 = wave_shr1(al1, NEGF); /* slot-1 : state g0-1 */          \
      float u0 = wave_shr1(al0, NEGF); /* slot-2 : state g0-2 */          \
      float na0 = lse3_2(al0, u1, sk[0] ? u0 : NEGF) + (PA);              \
      float na1 = lse3_2(al1, al0, sk[1] ? u1 : NEGF) + (PB);             \
      al0 = na0; al1 = na1;                                               \
    }                                                                     \
  } while (0)

  for (int t = 1; t < Tmax; t += 8) {
    int buf = (t >> 3) & 1;
    if (w4 < 3) {
      if (e0 >= 0 && e0 < 16) bnd[buf][grp][w4][e0] = al0;
      int e1 = e0 + 1;
      if (e1 >= 0 && e1 < 16) bnd[buf][grp][w4][e1] = al1;
    }
    __syncthreads();
    if (w4 > 0 && lane < 8) {
      al0 = bnd[buf][grp][w4 - 1][2 * lane];
      al1 = bnd[buf][grp][w4 - 1][2 * lane + 1];
    }
    STEP(t,     a_lo0.y, b_lo0.y);
    STEP(t + 1, a_lo0.z, b_lo0.z);
    STEP(t + 2, a_lo0.w, b_lo0.w);
    STEP(t + 3, a_lo1.x, b_lo1.x);
    STEP(t + 4, a_lo1.y, b_lo1.y);
    STEP(t + 5, a_lo1.z, b_lo1.z);
    STEP(t + 6, a_lo1.w, b_lo1.w);
    STEP(t + 7, a_hi0.x, b_hi0.x);
    a_lo0 = a_hi0; a_lo1 = a_hi1;
    b_lo0 = b_hi0; b_lo1 = b_hi1;
    int tn = t + 15;  // = 8k+16, 16B-aligned offset
    a_hi0 = *(const float4*)(pa + tn); a_hi1 = *(const float4*)(pa + tn + 4);
    b_hi0 = *(const float4*)(pb + tn); b_hi1 = *(const float4*)(pb + tn + 4);
  }

  {
    int slot0 = 2 * lane;
    if (slot0 >= h && slot0 < h + 101 && g0 >= 0 && g0 <= 400) sal[grp][g0] = al0;
    int slot1 = slot0 + 1, g1 = g0 + 1;
    if (slot1 >= h && slot1 < h + 101 && g1 <= 400) sal[grp][g1] = al1;
  }
  __syncthreads();
  if (w4 == 0 && lane == 0) {
    float l1 = sal[grp][2 * Ub];
    float l2 = sal[grp][2 * Ub - 1];
    float m = fmaxf(l1, l2);
    float l2sum = m + flog2(fexp2(l1 - m) + fexp2(l2 - m));  // log2 domain
    lossout[b] = (-LN2 * l2sum) / (float)Tb;                  // back to nat log
  }
#undef STEP
}

__global__ void k_reduce(const float* __restrict__ lossv, float* __restrict__ out) {
  float v = lossv[threadIdx.x];
#pragma unroll
  for (int m = 1; m < 64; m <<= 1) v += __shfl_xor(v, m);
  if (threadIdx.x == 0) out[0] = v * (1.0f / 64.0f);
}

extern "C" void kernel_launch(void* const* d_in, const int* in_sizes, int n_in,
                              void* d_out, int out_size, void* d_ws, size_t ws_size,
                              hipStream_t stream) {
  const float* X  = (const float*)d_in[0];
  const int* tgt  = (const int*)d_in[1];
  const int* dlen = (const int*)d_in[2];
  const int* tlen = (const int*)d_in[3];
  const float* W1 = (const float*)d_in[4];
  const float* b1 = (const float*)d_in[5];
  const float* W2 = (const float*)d_in[6];
  const float* b2 = (const float*)d_in[7];

  char* ws = (char*)d_ws;
  float* LPT           = (float*)(ws + 33554432);            // 25,856,000 B
  unsigned short* W1bf = (unsigned short*)(ws + 131072000);  // 1,048,576 B
  unsigned short* W2bf = (unsigned short*)(ws + 132120576);  // 131,072 B
  unsigned short* Hbf  = (unsigned short*)(ws + 132251648);  // 65,536,000 B
  float* lossv         = (float*)(ws + 197787648);           // 256 B

  k_cvt<<<512, 256, 0, stream>>>(W1, W1bf, 524288L);
  k_cvt_w2<<<64, 256, 0, stream>>>(W2, W2bf);
  k_gemm1f<<<500, 512, 0, stream>>>(X, W1bf, b1, dlen, Hbf);
  k_gemm2<<<500, 256, 0, stream>>>(Hbf, W2bf, b2, dlen, LPT);
  k_ctc<<<32, 512, 0, stream>>>(LPT, tgt, dlen, tlen, lossv);
  k_reduce<<<1, 64, 0, stream>>>(lossv, (float*)d_out);
}

// Round 21
// 234.667 us; speedup vs baseline: 1.2894x; 1.2894x over previous
//
#include <hip/hip_runtime.h>
#include <cstdint>
#include <cstddef>

#define NEGF (-1e30f)
#define LOG2E 1.4426950408889634f
#define LN2 0.6931471805599453f

typedef __attribute__((ext_vector_type(8))) short short8;
typedef __attribute__((ext_vector_type(4))) float f32x4;

// round-to-nearest-even fp32 -> bf16 bits
__device__ __forceinline__ unsigned short f2bf(float f) {
  unsigned int u = __float_as_uint(f);
  u += 0x7fffu + ((u >> 16) & 1u);
  return (unsigned short)(u >> 16);
}

__device__ __forceinline__ void gload_lds16(const void* g, void* l) {
  __builtin_amdgcn_global_load_lds(
      (const __attribute__((address_space(1))) void*)g,
      (__attribute__((address_space(3))) void*)l, 16, 0, 0);
}

__device__ __forceinline__ float fexp2(float x) { return __builtin_amdgcn_exp2f(x); }
__device__ __forceinline__ float flog2(float x) { return __builtin_amdgcn_logf(x); }

// full-wave shift-up-by-1 via DPP wave_shr:1 (full-rate VALU).
// lane i gets lane i-1; lane 0 gets `fill` (old operand, bound_ctrl=false).
__device__ __forceinline__ float wave_shr1(float x, float fill) {
  int r = __builtin_amdgcn_update_dpp(__float_as_int(fill), __float_as_int(x),
                                      0x138, 0xF, 0xF, false);
  return __int_as_float(r);
}

// log-sum-exp of 3 in log2 domain; max term is exp2(0)=1 exactly -> only 2 exp2.
__device__ __forceinline__ float lse3_2(float a, float b, float c) {
  float m  = fmaxf(fmaxf(a, b), c);                 // v_max3
  float md = __builtin_amdgcn_fmed3f(a, b, c);      // v_med3
  float mn = fminf(fminf(a, b), c);                 // v_min3
  return m + flog2(fexp2(md - m) + fexp2(mn - m) + 1.0f);
}

// ---------------- convert kernels (W1, W2 only; X is fused into gemm1f) ----------------
__global__ void k_cvt(const float* __restrict__ src, unsigned short* __restrict__ dst, long n) {
  long i = ((long)blockIdx.x * blockDim.x + threadIdx.x) * 4;
  long stride = (long)gridDim.x * blockDim.x * 4;
  for (; i < n; i += stride) {
    float4 v = *(const float4*)(src + i);
    ushort4 o;
    o.x = f2bf(v.x); o.y = f2bf(v.y); o.z = f2bf(v.z); o.w = f2bf(v.w);
    *(ushort4*)(dst + i) = o;
  }
}

// W2 [101][512] fp32 -> padded [128][512] bf16 (rows >=101 zero)
__global__ void k_cvt_w2(const float* __restrict__ w2, unsigned short* __restrict__ dst) {
  int i = (blockIdx.x * blockDim.x + threadIdx.x) * 4;
  if (i >= 128 * 512) return;
  int c = i >> 9;
  float4 v = make_float4(0.f, 0.f, 0.f, 0.f);
  if (c < 101) v = *(const float4*)(w2 + i);
  ushort4 o;
  o.x = f2bf(v.x); o.y = f2bf(v.y); o.z = f2bf(v.z); o.w = f2bf(v.w);
  *(ushort4*)(dst + i) = o;
}

// ---------------- GEMM1 (fused X-convert): H = relu(X @ W1^T + b1) ----------------
// DEAD-ROW SKIP + X-PREFETCH PIPELINE: X tile for kt+1 is issued AFTER the mid
// barrier so its ~600-900cyc HBM latency hides under the MFMA phase; the next
// top __syncthreads' implicit vmcnt(0) is the wait the cvt needed anyway.
__global__ __launch_bounds__(512, 1) void k_gemm1f(
    const float* __restrict__ X,
    const unsigned short* __restrict__ B,
    const float* __restrict__ b1,
    const int* __restrict__ dlen,
    unsigned short* __restrict__ H) {
  __shared__ __align__(16) char ldsA[128 * 144];   // 18432 B
  __shared__ __align__(16) char ldsB[65536];       // [512][64] bf16
  const int K = 1024;
  int r0 = blockIdx.x * 128;
  {
    int b0 = r0 / 1000;
    int rl = r0 - b0 * 1000;
    if (rl <= 872 && rl >= dlen[b0]) return;
  }
  int tid = threadIdx.x;
  int lane = tid & 63, wid = tid >> 6;   // 8 waves
  int wr = (wid & 1) * 64;               // wave row offset: 0 or 64
  int wc = (wid >> 1) * 128;             // wave col offset: 0,128,256,384

  f32x4 acc[4][8];
#pragma unroll
  for (int i = 0; i < 4; ++i)
#pragma unroll
    for (int j = 0; j < 8; ++j) acc[i][j] = (f32x4){0.f, 0.f, 0.f, 0.f};

  int arow = tid >> 2;           // 0..127
  int akoff = (tid & 3) * 16;    // float offset within BK=64: 0,16,32,48
  const float* apbase = X + (size_t)(r0 + arow) * K + akoff;

  // preload kt=0's A tile into registers
  float4 av0 = *(const float4*)(apbase + 0);
  float4 av1 = *(const float4*)(apbase + 4);
  float4 av2 = *(const float4*)(apbase + 8);
  float4 av3 = *(const float4*)(apbase + 12);

  for (int kt = 0; kt < 16; ++kt) {
    int k0 = kt * 64;
    __syncthreads();   // also waits the in-flight A-prefetch (almost landed)
    // stage A from prefetched regs: 16 bf16, two b128 writes, stride-144 layout
    {
      short8 as0, as1;
      as0[0] = (short)f2bf(av0.x); as0[1] = (short)f2bf(av0.y);
      as0[2] = (short)f2bf(av0.z); as0[3] = (short)f2bf(av0.w);
      as0[4] = (short)f2bf(av1.x); as0[5] = (short)f2bf(av1.y);
      as0[6] = (short)f2bf(av1.z); as0[7] = (short)f2bf(av1.w);
      as1[0] = (short)f2bf(av2.x); as1[1] = (short)f2bf(av2.y);
      as1[2] = (short)f2bf(av2.z); as1[3] = (short)f2bf(av2.w);
      as1[4] = (short)f2bf(av3.x); as1[5] = (short)f2bf(av3.y);
      as1[6] = (short)f2bf(av3.z); as1[7] = (short)f2bf(av3.w);
      int ab = arow * 144 + akoff * 2;
      *(short8*)(ldsA + ab) = as0;
      *(short8*)(ldsA + ab + 16) = as1;
    }
    // stage B: 512x64 bf16 via gload_lds, pre-swizzled source chunks
#pragma unroll
    for (int r = 0; r < 8; ++r) {
      int c = r * 512 + tid;
      int trow = c >> 3;                  // 0..511 (output col)
      int sch = (c & 7) ^ (trow & 7);
      gload_lds16(B + (size_t)trow * K + (k0 + sch * 8), ldsB + c * 16);
    }
    asm volatile("s_waitcnt vmcnt(0)" ::: "memory");
    __syncthreads();
    // issue next A tile now -> latency hides under the MFMA phase below
    if (kt < 15) {
      const float* apn = apbase + (kt + 1) * 64;
      av0 = *(const float4*)(apn + 0);
      av1 = *(const float4*)(apn + 4);
      av2 = *(const float4*)(apn + 8);
      av3 = *(const float4*)(apn + 12);
    }
#pragma unroll
    for (int kk = 0; kk < 2; ++kk) {
      int kb2 = (kk * 32 + ((lane >> 4) << 3)) * 2;  // byte offset along K
      short8 af[4], bfr[8];
#pragma unroll
      for (int i = 0; i < 4; ++i) {
        int ar = wr + i * 16 + (lane & 15);
        af[i] = *(const short8*)(ldsA + (ar * 144 + kb2));
      }
#pragma unroll
      for (int j = 0; j < 8; ++j) {
        int br = wc + j * 16 + (lane & 15);
        bfr[j] = *(const short8*)(ldsB + ((br * 128 + kb2) ^ ((br & 7) << 4)));
      }
#pragma unroll
      for (int i = 0; i < 4; ++i)
#pragma unroll
        for (int j = 0; j < 8; ++j)
          acc[i][j] = __builtin_amdgcn_mfma_f32_16x16x32_bf16(af[i], bfr[j], acc[i][j], 0, 0, 0);
    }
  }
  int cl = lane & 15, r4 = (lane >> 4) << 2;
#pragma unroll
  for (int i = 0; i < 4; ++i) {
    int row = r0 + wr + i * 16 + r4;
#pragma unroll
    for (int j = 0; j < 8; ++j) {
      int col = wc + j * 16 + cl;
      float bb = b1[col];
#pragma unroll
      for (int q = 0; q < 4; ++q) {
        float v = acc[i][j][q] + bb;
        v = v > 0.f ? v : 0.f;
        H[(size_t)(row + q) * 512 + col] = f2bf(v);
      }
    }
  }
}

// ---------------- GEMM2 + log_softmax + FUSED TRANSPOSE ----------------
// Hm[64000][512] bf16, W2[128][512] bf16 (padded); writes LPT[b][c][t] fp32*log2e
// directly (acc q-dim = 4 consecutive t at fixed col -> one aligned float4).
__global__ __launch_bounds__(256) void k_gemm2(
    const unsigned short* __restrict__ Hm,
    const unsigned short* __restrict__ W2,
    const float* __restrict__ b2,
    const int* __restrict__ dlen,
    float* __restrict__ LPT) {
  __shared__ __align__(16) char lds[32768];
  const int K = 512;
  int row0 = blockIdx.x * 128;
  {
    int b0 = row0 / 1000;
    int rl = row0 - b0 * 1000;
    if (rl <= 872 && rl >= dlen[b0]) return;
  }
  int tid = threadIdx.x, lane = tid & 63, wid = tid >> 6;
  f32x4 acc[2][8];
#pragma unroll
  for (int i = 0; i < 2; ++i)
#pragma unroll
    for (int j = 0; j < 8; ++j) acc[i][j] = (f32x4){0.f, 0.f, 0.f, 0.f};

  for (int kt = 0; kt < 8; ++kt) {
    int k0 = kt * 64;
    __syncthreads();
#pragma unroll
    for (int r = 0; r < 4; ++r) {
      int c = r * 256 + tid;
      int trow = c >> 3;
      int sch = (c & 7) ^ (trow & 7);
      gload_lds16(Hm + (size_t)(row0 + trow) * K + (k0 + sch * 8), lds + c * 16);
      gload_lds16(W2 + (size_t)trow * K + (k0 + sch * 8), lds + 16384 + c * 16);
    }
    asm volatile("s_waitcnt vmcnt(0)" ::: "memory");
    __syncthreads();
#pragma unroll
    for (int kk = 0; kk < 2; ++kk) {
      int kb2 = (kk * 32 + ((lane >> 4) << 3)) * 2;
      short8 af[2], bfr[8];
#pragma unroll
      for (int i = 0; i < 2; ++i) {
        int ar = wid * 32 + i * 16 + (lane & 15);
        af[i] = *(const short8*)(lds + ((ar * 128 + kb2) ^ ((ar & 7) << 4)));
      }
#pragma unroll
      for (int j = 0; j < 8; ++j) {
        int br = j * 16 + (lane & 15);
        bfr[j] = *(const short8*)(lds + 16384 + ((br * 128 + kb2) ^ ((br & 7) << 4)));
      }
#pragma unroll
      for (int i = 0; i < 2; ++i)
#pragma unroll
        for (int j = 0; j < 8; ++j)
          acc[i][j] = __builtin_amdgcn_mfma_f32_16x16x32_bf16(af[i], bfr[j], acc[i][j], 0, 0, 0);
    }
  }
  // epilogue: bias + row log_softmax (per q), then transposed float4 stores
  int cl = lane & 15, r4 = (lane >> 4) << 2;
#pragma unroll
  for (int i = 0; i < 2; ++i) {
    float outv[4][8];
#pragma unroll
    for (int q = 0; q < 4; ++q) {
      float v[8];
      float mx = NEGF;
#pragma unroll
      for (int j = 0; j < 8; ++j) {
        int col = j * 16 + cl;
        float t = acc[i][j][q];
        if (col < 101) {
          t += b2[col];
          mx = fmaxf(mx, t);
        }
        v[j] = t;
      }
#pragma unroll
      for (int m = 1; m < 16; m <<= 1) mx = fmaxf(mx, __shfl_xor(mx, m));
      float s = 0.f;
#pragma unroll
      for (int j = 0; j < 8; ++j) {
        int col = j * 16 + cl;
        if (col < 101) s += __expf(v[j] - mx);
      }
#pragma unroll
      for (int m = 1; m < 16; m <<= 1) s += __shfl_xor(s, m);
      float lse = mx + __logf(s);
#pragma unroll
      for (int j = 0; j < 8; ++j) outv[q][j] = (v[j] - lse) * LOG2E;
    }
    int row = row0 + wid * 32 + i * 16 + r4;  // base row for q=0..3
    int bb = row / 1000;
    int t = row - bb * 1000;                   // multiple of 4
    float* outp = LPT + (size_t)bb * 101000 + t;
#pragma unroll
    for (int j = 0; j < 8; ++j) {
      int col = j * 16 + cl;
      if (col < 101) {
        float4 o = make_float4(outv[0][j], outv[1][j], outv[2][j], outv[3][j]);
        *(float4*)(outp + col * 1000) = o;
      }
    }
  }
}

// ---------------- CTC alpha recursion: 4 waves, halo exchange every 8 steps ----------------
// Round-17 verified version: log2 domain, DPP wave_shr1, streaming LPT reads.
__global__ __launch_bounds__(256, 1) void k_ctc(
    const float* __restrict__ LPT,
    const int* __restrict__ tgt_all,
    const int* __restrict__ dlen,
    const int* __restrict__ tlen,
    float* __restrict__ lossout) {
  int b = blockIdx.x;
  int tid = threadIdx.x;
  int lane = tid & 63, wid = tid >> 6;
  const float* lpt = LPT + (size_t)b * 101000;
  int Tb = dlen[b];
  int Ub = tlen[b];
  const int* tg = tgt_all + b * 200;

  int h = (wid == 0) ? 0 : 16;
  int S0 = 101 * wid - h;
  int g0 = S0 + 2 * lane;  // state of al0; al1 is g0+1

  int cls[2], sk[2];
#pragma unroll
  for (int j = 0; j < 2; ++j) {
    int s = g0 + j;
    int c = 100, skp = 0;
    if (s >= 0 && s < 401 && (s & 1)) {
      int u = (s - 1) >> 1;
      c = tg[u];
      if (s >= 3) skp = (tg[u] != tg[u - 1]) ? 1 : 0;
    }
    cls[j] = c; sk[j] = skp;
  }

  const float* pa = lpt + cls[0] * 1000;  // 16B-aligned class rows
  const float* pb = lpt + cls[1] * 1000;

  float al0 = (g0 == 0) ? pa[0] : NEGF;  // t=0: only s=0,1 start
  float al1 = (g0 == 0) ? pb[0] : NEGF;

  int slot_base = (wid == 0) ? 85 : 101;
  int e0 = 2 * lane - slot_base;  // for al0; al1 -> e0+1

  __shared__ float bnd[2][3][16];  // [buf][producer wave][16 boundary states]
  __shared__ float sal[408];

  // rotating 2-block prefetch: lo = rows [8k,8k+8), hi = rows [8k+8,8k+16)
  float4 a_lo0 = *(const float4*)(pa + 0),  a_lo1 = *(const float4*)(pa + 4);
  float4 a_hi0 = *(const float4*)(pa + 8),  a_hi1 = *(const float4*)(pa + 12);
  float4 b_lo0 = *(const float4*)(pb + 0),  b_lo1 = *(const float4*)(pb + 4);
  float4 b_hi0 = *(const float4*)(pb + 8),  b_hi1 = *(const float4*)(pb + 12);

#define STEP(tt, PA, PB)                                                  \
  do {                                                                    \
    if ((tt) < Tb) {                                                      \
      float u1 = wave_shr1(al1, NEGF); /* slot-1 : state g0-1 */          \
      float u0 = wave_shr1(al0, NEGF); /* slot-2 : state g0-2 */          \
      float na0 = lse3_2(al0, u1, sk[0] ? u0 : NEGF) + (PA);              \
      float na1 = lse3_2(al1, al0, sk[1] ? u1 : NEGF) + (PB);             \
      al0 = na0; al1 = na1;                                               \
    }                                                                     \
  } while (0)

  for (int t = 1; t < Tb; t += 8) {
    int buf = (t >> 3) & 1;
    if (wid < 3) {
      if (e0 >= 0 && e0 < 16) bnd[buf][wid][e0] = al0;
      int e1 = e0 + 1;
      if (e1 >= 0 && e1 < 16) bnd[buf][wid][e1] = al1;
    }
    __syncthreads();
    if (wid > 0 && lane < 8) {
      al0 = bnd[buf][wid - 1][2 * lane];
      al1 = bnd[buf][wid - 1][2 * lane + 1];
    }
    STEP(t,     a_lo0.y, b_lo0.y);
    STEP(t + 1, a_lo0.z, b_lo0.z);
    STEP(t + 2, a_lo0.w, b_lo0.w);
    STEP(t + 3, a_lo1.x, b_lo1.x);
    STEP(t + 4, a_lo1.y, b_lo1.y);
    STEP(t + 5, a_lo1.z, b_lo1.z);
    STEP(t + 6, a_lo1.w, b_lo1.w);
    STEP(t + 7, a_hi0.x, b_hi0.x);
    a_lo0 = a_hi0; a_lo1 = a_hi1;
    b_lo0 = b_hi0; b_lo1 = b_hi1;
    int tn = t + 15;  // = 8k+16, 16B-aligned offset
    a_hi0 = *(const float4*)(pa + tn); a_hi1 = *(const float4*)(pa + tn + 4);
    b_hi0 = *(const float4*)(pb + tn); b_hi1 = *(const float4*)(pb + tn + 4);
  }

  {
    int slot0 = 2 * lane;
    if (slot0 >= h && slot0 < h + 101 && g0 >= 0 && g0 <= 400) sal[g0] = al0;
    int slot1 = slot0 + 1, g1 = g0 + 1;
    if (slot1 >= h && slot1 < h + 101 && g1 <= 400) sal[g1] = al1;
  }
  __syncthreads();
  if (tid == 0) {
    float l1 = sal[2 * Ub];
    float l2 = sal[2 * Ub - 1];
    float m = fmaxf(l1, l2);
    float l2sum = m + flog2(fexp2(l1 - m) + fexp2(l2 - m));  // log2 domain
    lossout[b] = (-LN2 * l2sum) / (float)Tb;                  // back to nat log
  }
#undef STEP
}

__global__ void k_reduce(const float* __restrict__ lossv, float* __restrict__ out) {
  float v = lossv[threadIdx.x];
#pragma unroll
  for (int m = 1; m < 64; m <<= 1) v += __shfl_xor(v, m);
  if (threadIdx.x == 0) out[0] = v * (1.0f / 64.0f);
}

extern "C" void kernel_launch(void* const* d_in, const int* in_sizes, int n_in,
                              void* d_out, int out_size, void* d_ws, size_t ws_size,
                              hipStream_t stream) {
  const float* X  = (const float*)d_in[0];
  const int* tgt  = (const int*)d_in[1];
  const int* dlen = (const int*)d_in[2];
  const int* tlen = (const int*)d_in[3];
  const float* W1 = (const float*)d_in[4];
  const float* b1 = (const float*)d_in[5];
  const float* W2 = (const float*)d_in[6];
  const float* b2 = (const float*)d_in[7];

  char* ws = (char*)d_ws;
  float* LPT           = (float*)(ws + 33554432);            // 25,856,000 B
  unsigned short* W1bf = (unsigned short*)(ws + 131072000);  // 1,048,576 B
  unsigned short* W2bf = (unsigned short*)(ws + 132120576);  // 131,072 B
  unsigned short* Hbf  = (unsigned short*)(ws + 132251648);  // 65,536,000 B
  float* lossv         = (float*)(ws + 197787648);           // 256 B

  k_cvt<<<512, 256, 0, stream>>>(W1, W1bf, 524288L);
  k_cvt_w2<<<64, 256, 0, stream>>>(W2, W2bf);
  k_gemm1f<<<500, 512, 0, stream>>>(X, W1bf, b1, dlen, Hbf);
  k_gemm2<<<500, 256, 0, stream>>>(Hbf, W2bf, b2, dlen, LPT);
  k_ctc<<<64, 256, 0, stream>>>(LPT, tgt, dlen, tlen, lossv);
  k_reduce<<<1, 64, 0, stream>>>(lossv, (float*)d_out);
}